// Round 3
// baseline (564.190 us; speedup 1.0000x reference)
//
#include <hip/hip_runtime.h>

#define QMAX 127.0f
#define B_   64
#define C_   1024
#define HW_  784
#define R_   256
#define NROW 65536                 // B*C
#define NBLK 512

typedef float fx4 __attribute__((ext_vector_type(4)));   // native vec: nontemporal st OK

// ws float offsets
#define PX_OFF   0                 // 512 per-block partial max |x|
#define PW1_OFF  512               // 512 partial max |W1|
#define PW2_OFF  1024              // 512 partial max |W2|
#define PM_OFF   1536              // 512 partial max |mean|
#define PH_OFF   2048              // 512 partial max h
#define CNT_OFF  2560              // 4 ints (16 B), zeroed by hipMemsetAsync each launch
#define MEAN_OFF 4096              // 65536 floats
#define H_OFF    (MEAN_OFF + NROW) // 16384 floats

__device__ __forceinline__ float block_max(float v, volatile float* sm) {
    #pragma unroll
    for (int o = 32; o > 0; o >>= 1) v = fmaxf(v, __shfl_xor(v, o, 64));
    int lane = threadIdx.x & 63, wid = threadIdx.x >> 6;
    if (lane == 0) sm[wid] = v;
    __syncthreads();
    float r = fmaxf(fmaxf(sm[0], sm[1]), fmaxf(sm[2], sm[3]));
    __syncthreads();               // safe for helper reuse
    return r;
}

__device__ __forceinline__ float amax4(float4 v) {
    return fmaxf(fmaxf(fabsf(v.x), fabsf(v.y)), fmaxf(fabsf(v.z), fabsf(v.w)));
}

// quantize -> float-held integer (exact: |q| <= 127, dot sums <= 1024*127^2 = 16.5M < 2^24).
__device__ __forceinline__ float qf(float v, float rs) {
    return fminf(fmaxf(rintf(v * rs), -QMAX), QMAX);   // v_med3_f32 clamp
}
__device__ __forceinline__ float q4f(float4 v, float rs) {
    return qf(v.x, rs) + qf(v.y, rs) + qf(v.z, rs) + qf(v.w, rs);
}

// Graph-capture-safe grid barrier: device-scope atomic counter + spin.
// All 512 blocks are co-resident (2 blocks/CU guaranteed by __launch_bounds__(256,2):
// VGPR<=256 -> >=2 waves/SIMD -> >=8 waves/CU -> 2 blocks of 4 waves). No deadlock.
__device__ __forceinline__ void gsync(int* cnt, int target) {
    __syncthreads();                                   // all block writes complete (vmcnt(0))
    if (threadIdx.x == 0) {
        __threadfence();                               // agent-scope release (L2 writeback, cross-XCD)
        __hip_atomic_fetch_add(cnt, 1, __ATOMIC_RELEASE, __HIP_MEMORY_SCOPE_AGENT);
        while (__hip_atomic_load(cnt, __ATOMIC_ACQUIRE, __HIP_MEMORY_SCOPE_AGENT) < target)
            __builtin_amdgcn_s_sleep(1);               // acquire invalidates L1/L2 on exit
    }
    __syncthreads();
}

// Single fused kernel: A(absmax) -> B(quant mean) -> C(FC1+relu) -> D(FC2+gate+scale)
__global__ __launch_bounds__(256, 2) void kFused(
        const float* __restrict__ x,
        const float* __restrict__ W1, const float* __restrict__ b1,
        const float* __restrict__ W2, const float* __restrict__ b2,
        float* __restrict__ ws, float* __restrict__ out)
{
    __shared__ float sm[4];
    const int t = threadIdx.x;
    const int lane = t & 63, wid = t >> 6;
    const int bid = blockIdx.x;
    int* cnt = (int*)(ws + CNT_OFF);

    // ---------- Phase A: absmax partials of x, W1, W2 ----------
    {
        const float4* x4 = (const float4*)x;
        int tid = bid * 256 + t;                        // 131072 threads
        float mx = 0.0f;
        #pragma unroll 7                                // 98 = 7*14 exact
        for (int j = 0; j < 98; j++) mx = fmaxf(mx, amax4(x4[tid + j * 131072]));
        float m1 = 0.0f, m2 = 0.0f;
        if (tid < 65536) {
            m1 = amax4(((const float4*)W1)[tid]);
            m2 = amax4(((const float4*)W2)[tid]);
        }
        float bx = block_max(mx, sm);
        float p1 = block_max(m1, sm);
        float p2 = block_max(m2, sm);
        if (t == 0) {
            ws[PX_OFF  + bid] = bx;
            ws[PW1_OFF + bid] = p1;
            ws[PW2_OFF + bid] = p2;
        }
    }
    gsync(cnt + 0, NBLK);

    // ---------- Phase B: quantized per-(b,c) mean + |mean| partials ----------
    {
        const float* px = ws + PX_OFF;
        float gmax = block_max(fmaxf(px[t], px[t + 256]), sm);
        float s  = fmaxf(gmax / QMAX, 1e-8f);
        float rs = 1.0f / s;
        int gw = bid * 4 + wid;                         // 2048 waves, 32 rows each
        float wmax = 0.0f;
        #pragma unroll 2
        for (int k = 0; k < 32; k++) {
            int bc = gw * 32 + k;
            const float4* p = (const float4*)(x + (size_t)bc * HW_);
            float fs = q4f(p[lane], rs) + q4f(p[lane + 64], rs) + q4f(p[lane + 128], rs);
            if (lane < 4) fs += q4f(p[192 + lane], rs);
            #pragma unroll
            for (int o = 32; o > 0; o >>= 1) fs += __shfl_xor(fs, o, 64);
            float m = fs * s / 784.0f;                  // exact int-sum * s
            if (lane == 0) ws[MEAN_OFF + bc] = m;
            wmax = fmaxf(wmax, fabsf(m));
        }
        float bm = block_max(wmax, sm);
        if (t == 0) ws[PM_OFF + bid] = bm;
    }
    gsync(cnt + 1, NBLK);

    // ---------- Phase C: FC1 + relu + h partials ----------
    {
        const float* pm = ws + PM_OFF;
        const float* pw = ws + PW1_OFF;
        float mmax = block_max(fmaxf(pm[t], pm[t + 256]), sm);
        float wmx  = block_max(fmaxf(pw[t], pw[t + 256]), sm);
        float s2 = fmaxf(mmax / QMAX, 1e-8f);           // double fake-quant == single (max q = 127)
        float sw = fmaxf(wmx / QMAX, 1e-8f);
        float rs2 = 1.0f / s2, rsw = 1.0f / sw;
        int gw = bid * 4 + wid;                         // 2048 waves, 8 outputs each
        int b = gw >> 5;                                // all 8 outputs share one batch
        const float4* mrow = (const float4*)(ws + MEAN_OFF + b * C_);
        float qm[16];
        #pragma unroll
        for (int j = 0; j < 4; j++) {                   // load + quantize mean row ONCE
            float4 mv = mrow[lane + 64 * j];
            qm[4*j+0] = qf(mv.x, rs2); qm[4*j+1] = qf(mv.y, rs2);
            qm[4*j+2] = qf(mv.z, rs2); qm[4*j+3] = qf(mv.w, rs2);
        }
        float hmax = 0.0f;
        #pragma unroll 2
        for (int k = 0; k < 8; k++) {
            int outn = gw * 8 + k;                      // 16384 outputs
            int r = outn & 255;
            const float4* wrow = (const float4*)(W1 + r * C_);
            float fdot = 0.0f;
            #pragma unroll
            for (int j = 0; j < 4; j++) {
                float4 wv = wrow[lane + 64 * j];
                fdot = fmaf(qm[4*j+0], qf(wv.x, rsw), fdot);
                fdot = fmaf(qm[4*j+1], qf(wv.y, rsw), fdot);
                fdot = fmaf(qm[4*j+2], qf(wv.z, rsw), fdot);
                fdot = fmaf(qm[4*j+3], qf(wv.w, rsw), fdot);
            }
            #pragma unroll
            for (int o = 32; o > 0; o >>= 1) fdot += __shfl_xor(fdot, o, 64);
            float hv = fmaxf(fdot * (s2 * sw) + b1[r], 0.0f);
            if (lane == 0) ws[H_OFF + outn] = hv;
            hmax = fmaxf(hmax, hv);
        }
        float bh = block_max(hmax, sm);
        if (t == 0) ws[PH_OFF + bid] = bh;
    }
    gsync(cnt + 2, NBLK);

    // ---------- Phase D: FC2 + hardsigmoid + scale + store ----------
    {
        const float* ph = ws + PH_OFF;
        const float* pw = ws + PW2_OFF;
        float hmx = block_max(fmaxf(ph[t], ph[t + 256]), sm);
        float wmx = block_max(fmaxf(pw[t], pw[t + 256]), sm);
        float sh = fmaxf(hmx / QMAX, 1e-8f);            // h is raw (single fake_quant)
        float sw = fmaxf(wmx / QMAX, 1e-8f);
        float rsh = 1.0f / sh, rsw = 1.0f / sw;
        int gw = bid * 4 + wid;                         // 2048 waves, 32 rows each
        int bc0 = gw * 32;
        int b = gw >> 5;                                // 32 rows share one batch
        const float4* hrow = (const float4*)(ws + H_OFF + b * R_);
        float4 hv4 = hrow[lane];                        // full h[b,:] across wave, loaded once
        float qh_x = qf(hv4.x, rsh), qh_y = qf(hv4.y, rsh);
        float qh_z = qf(hv4.z, rsh), qh_w = qf(hv4.w, rsh);
        #pragma unroll 2
        for (int k = 0; k < 32; k++) {
            int bc = bc0 + k;
            int c = bc & 1023;
            const float4* wrow = (const float4*)(W2 + c * R_);
            float4 wv = wrow[lane];
            float fdot =      qh_x * qf(wv.x, rsw);
            fdot = fmaf(qh_y, qf(wv.y, rsw), fdot);
            fdot = fmaf(qh_z, qf(wv.z, rsw), fdot);
            fdot = fmaf(qh_w, qf(wv.w, rsw), fdot);
            #pragma unroll
            for (int o = 32; o > 0; o >>= 1) fdot += __shfl_xor(fdot, o, 64);
            float tv = fdot * (sh * sw) + b2[c];
            float g = fminf(fmaxf(tv / 6.0f + 0.5f, 0.0f), 1.0f);
            const fx4* p = (const fx4*)(x + (size_t)bc * HW_);
            fx4* o4 = (fx4*)(out + (size_t)bc * HW_);
            #pragma unroll
            for (int j = 0; j < 3; j++) {
                fx4 v = p[lane + 64 * j];               // x likely L3-hot: cached load
                v *= g;
                __builtin_nontemporal_store(v, &o4[lane + 64 * j]);
            }
            if (lane < 4) {
                fx4 v = p[192 + lane];
                v *= g;
                __builtin_nontemporal_store(v, &o4[192 + lane]);
            }
        }
    }
}

extern "C" void kernel_launch(void* const* d_in, const int* in_sizes, int n_in,
                              void* d_out, int out_size, void* d_ws, size_t ws_size,
                              hipStream_t stream) {
    const float* x  = (const float*)d_in[0];
    const float* W1 = (const float*)d_in[1];
    const float* b1 = (const float*)d_in[2];
    const float* W2 = (const float*)d_in[3];
    const float* b2 = (const float*)d_in[4];
    float* out = (float*)d_out;
    float* ws  = (float*)d_ws;

    // zero the 4 barrier counters (16 B) -- memset nodes are graph-capturable
    hipMemsetAsync((char*)d_ws + CNT_OFF * 4, 0, 16, stream);
    kFused<<<NBLK, 256, 0, stream>>>(x, W1, b1, W2, b2, ws, out);
}